// Round 2
// baseline (335.355 us; speedup 1.0000x reference)
//
#include <hip/hip_runtime.h>
#include <stdint.h>

// Problem constants (from reference setup_inputs)
#define B_DIM   16384
#define IN_DIM  2048
#define OUT_DIM 2048
#define BN_EPS  1e-5f

typedef int    i32x4 __attribute__((ext_vector_type(4)));
typedef unsigned short u16x4 __attribute__((ext_vector_type(4)));

// ---------- helpers ----------

__device__ __forceinline__ unsigned short f2bf_rne(float f) {
    unsigned u = __builtin_bit_cast(unsigned, f);
    return (unsigned short)((u + 0x7fffu + ((u >> 16) & 1u)) >> 16);
}
__device__ __forceinline__ float bf2f(unsigned short h) {
    unsigned u = ((unsigned)h) << 16;
    return __builtin_bit_cast(float, u);
}

// async global->LDS, 16B per lane. LDS dst = wave-uniform base + lane*16.
__device__ __forceinline__ void gl_lds16(const void* g, void* l) {
    __builtin_amdgcn_global_load_lds(
        (const __attribute__((address_space(1))) unsigned int*)g,
        (__attribute__((address_space(3))) unsigned int*)l,
        16, 0, 0);
}

__device__ __forceinline__ int pack4(float a, float b, float c, float d, float inv) {
    int q0 = (int)rintf(a * inv) & 255;
    int q1 = (int)rintf(b * inv) & 255;
    int q2 = (int)rintf(c * inv) & 255;
    int q3 = (int)rintf(d * inv) & 255;
    return q0 | (q1 << 8) | (q2 << 16) | (q3 << 24);
}

// ---------- kernel 1: x fp32 -> i8 with per-row scale ----------
__global__ __launch_bounds__(256) void quantize_x_kernel(
        const float4* __restrict__ x4, int* __restrict__ xq,
        float* __restrict__ scales) {
    __shared__ float wmax[4];
    const int row = blockIdx.x;
    const int t = threadIdx.x;
    const float4* xr = x4 + (size_t)row * 512;
    float4 a = xr[t];          // 16B coalesced
    float4 b = xr[t + 256];
    float m = fmaxf(fmaxf(fabsf(a.x), fabsf(a.y)), fmaxf(fabsf(a.z), fabsf(a.w)));
    m = fmaxf(m, fmaxf(fmaxf(fabsf(b.x), fabsf(b.y)), fmaxf(fabsf(b.z), fabsf(b.w))));
#pragma unroll
    for (int off = 32; off >= 1; off >>= 1) m = fmaxf(m, __shfl_xor(m, off));
    if ((t & 63) == 0) wmax[t >> 6] = m;
    __syncthreads();
    m = fmaxf(fmaxf(wmax[0], wmax[1]), fmaxf(wmax[2], wmax[3]));
    m = fmaxf(m, 1e-20f);                 // guard all-zero row
    const float inv = 127.0f / m;
    if (t == 0) scales[row] = m * (1.0f / 127.0f);
    int* xo = xq + (size_t)row * 512;
    xo[t]       = pack4(a.x, a.y, a.z, a.w, inv);   // 4B coalesced
    xo[t + 256] = pack4(b.x, b.y, b.z, b.w, inv);
}

// ---------- kernel 2: w fp32 -> sign i8 (+1/-1); also zero stat accums ----------
__global__ __launch_bounds__(256) void convert_w_kernel(
        const float4* __restrict__ w, int* __restrict__ wq,
        float4* __restrict__ stats /* colsum[2048]+colsumsq[2048] */) {
    int id = blockIdx.x * 256 + threadIdx.x;       // exact: 4096 blocks
    if (id < 1024) stats[id] = make_float4(0.f, 0.f, 0.f, 0.f);
    float4 a = w[id];
    int b0 = (a.x < 0.f) ? 0xFF : 0x01;
    int b1 = (a.y < 0.f) ? 0xFF : 0x01;
    int b2 = (a.z < 0.f) ? 0xFF : 0x01;
    int b3 = (a.w < 0.f) ? 0xFF : 0x01;
    wq[id] = b0 | (b1 << 8) | (b2 << 16) | (b3 << 24);
}

// ---------- kernel 3: i8 GEMM (NT) 256x128 tile, 2 blocks/CU, counted-vmcnt ----------
// A: [B_DIM, IN_DIM] i8; Bw: [OUT_DIM, IN_DIM] i8 (+1/-1). D = i32 exact dot;
// Y[m][n] = scales[m] * D[m][n], stored bf16; column sum/sumsq fp32 atomics.
//
// Round-2 theory: round 1's 8-phase lockstep at 1 block/CU SERIALIZES LDS and
// MFMA time globally (MfmaUtil stuck 34%). Fix = cross-block overlap:
//  - tile 256x128, BK=64; 512 thr = 8 waves (4M x 2N), 64x64 per wave
//    -> acc[4][4] = 64 regs -> <=128 regs/wave -> 4 waves/SIMD
//  - LDS 2 x 24 KB = 48 KB -> 2 blocks/CU co-resident (the overlap source)
//  - one phase per K-tile, 2 barriers, counted vmcnt(3): tile t+2's 3 loads
//    stay in flight across the barrier; never vmcnt(0) in steady state
//  - LDS swizzle for BK=64 (4 slots/row): slot ^= (row>>1)&3. Bank idx bits =
//    {row&1, slot, word}; rows {r, r+8} share (parity, slot) -> 2 lanes/bank
//    = free (m136). Applied on the global SOURCE chunk (linear gl_lds dest),
//    same XOR on the ds_read slot (both-sides rule).
__global__ __launch_bounds__(512, 4) void gemm_bn_kernel(
        const char* __restrict__ A, const char* __restrict__ Bw,
        const float* __restrict__ scales,
        unsigned short* __restrict__ Yb,
        float* __restrict__ colsum, float* __restrict__ colsumsq) {
    // per buffer: A[256][64] = 16 KB at +0, B[128][64] = 8 KB at +16384
    __shared__ __align__(16) char smem[2 * 24576];   // 48 KiB

    const int tid  = threadIdx.x;
    const int wave = tid >> 6;
    const int lane = tid & 63;
    const int wm = wave >> 1;         // 0..3 -> 64-row band of M
    const int wn = wave & 1;          // 0..1 -> 64-col band of N
    const int lr = lane & 15;
    const int lq = lane >> 4;

    // XCD swizzle (1024 blocks, 1024%8==0 -> simple bijection).
    // Each XCD: 8 consecutive M-tiles x all 16 N-tiles; for a fixed M-tile the
    // 16 N-tiles run consecutively -> A-tile (512 KB) L2-hot across 16 reuses.
    const int b  = blockIdx.x;                 // 0..1023
    const int lb = (b & 7) * 128 + (b >> 3);
    const int bm = (lb >> 4) * 256;            // 64 M tiles
    const int bn = (lb & 15) * 128;            // 16 N tiles

    // ---- staging addressing ----
    // sweep = 128 rows x 64 B = 8 KB = 512 thr x 16B; thread row = tid>>2,
    // slot = tid&3; source chunk = slot ^ ((row>>1)&3) = slot ^ ((tid>>3)&3).
    const int swz16 = (((tid & 3) ^ ((tid >> 3) & 3)) << 4);
    const char* gA0 = A  + (size_t)(bm + (tid >> 2)) * IN_DIM + swz16;  // rows 0-127
    const char* gA1 = gA0 + (size_t)128 * IN_DIM;                       // rows 128-255
    const char* gB0 = Bw + (size_t)(bn + (tid >> 2)) * IN_DIM + swz16;  // rows 0-127
    const int ldst = tid << 4;

    // ---- ds-read addressing ----
    // frag row = band + i*16 + lr (x64B); phys slot = lq ^ ((lr>>1)&3)
    const int ps   = ((lq ^ ((lr >> 1) & 3)) << 4);
    const int aoff = (wm * 64 + lr) * 64 + ps;            // frag i: +i*1024
    const int boff = 16384 + (wn * 64 + lr) * 64 + ps;    // frag j: +j*1024

    i32x4 acc[4][4];
#pragma unroll
    for (int i = 0; i < 4; ++i)
#pragma unroll
        for (int j = 0; j < 4; ++j) {
            i32x4 z = {0, 0, 0, 0};
            acc[i][j] = z;
        }

#define VM_WAIT(N) asm volatile("s_waitcnt vmcnt(" #N ")" ::: "memory")
#define BAR()      __builtin_amdgcn_s_barrier()
#define STAGE(buf_, k_) do {                                   \
    char* d = smem + (buf_) * 24576;                           \
    gl_lds16(gA0 + (k_), d + ldst);                            \
    gl_lds16(gA1 + (k_), d + 8192 + ldst);                     \
    gl_lds16(gB0 + (k_), d + 16384 + ldst);                    \
} while (0)

    // prologue: tiles 0,1 -> buffers 0,1; drain tile 0's 3 loads only
    STAGE(0, 0);
    STAGE(1, 64);
    VM_WAIT(3);
    BAR();

    const int NT = IN_DIM / 64;     // 32 K-tiles
#pragma unroll
    for (int t = 0; t < NT; ++t) {
        const int cur = t & 1;
        const char* Sb = smem + cur * 24576;
        i32x4 av[4], bv[4];
#pragma unroll
        for (int i = 0; i < 4; ++i)
            av[i] = *(const i32x4*)(Sb + aoff + i * 1024);
#pragma unroll
        for (int j = 0; j < 4; ++j)
            bv[j] = *(const i32x4*)(Sb + boff + j * 1024);

        __builtin_amdgcn_s_setprio(1);
#pragma unroll
        for (int i = 0; i < 4; ++i)
#pragma unroll
            for (int j = 0; j < 4; ++j)
                acc[i][j] = __builtin_amdgcn_mfma_i32_16x16x64_i8(
                    av[i], bv[j], acc[i][j], 0, 0, 0);
        __builtin_amdgcn_s_setprio(0);

        if (t + 2 < NT) {
            BAR();                              // all waves done reading Sb
            STAGE(cur, (size_t)(t + 2) * 64);   // overwrite with tile t+2
            VM_WAIT(3);                         // drain tile t+1; t+2 in flight
            BAR();                              // t+1 visible to all waves
        } else if (t + 1 < NT) {
            VM_WAIT(0);                         // drain final tile's loads
            BAR();
        }
    }

#undef STAGE
#undef VM_WAIT
#undef BAR

    // epilogue: y = scales[m] * acc (C/D layout: col = lr, row = lq*4 + r)
    float colS[4], colQ[4];
#pragma unroll
    for (int j = 0; j < 4; ++j) { colS[j] = 0.f; colQ[j] = 0.f; }

#pragma unroll
    for (int i = 0; i < 4; ++i) {
        const int row0 = bm + wm * 64 + i * 16 + lq * 4;
        float sc[4];
#pragma unroll
        for (int r = 0; r < 4; ++r) sc[r] = scales[row0 + r];
#pragma unroll
        for (int r = 0; r < 4; ++r) {
            size_t base = (size_t)(row0 + r) * OUT_DIM + bn + wn * 64 + lr;
#pragma unroll
            for (int j = 0; j < 4; ++j) {
                float v = (float)acc[i][j][r] * sc[r];
                Yb[base + j * 16] = f2bf_rne(v);
                colS[j] += v;
                colQ[j] += v * v;
            }
        }
    }

    // per-column partial sum / sumsq -> atomics (combine 4 quads = 4 row groups)
#pragma unroll
    for (int j = 0; j < 4; ++j) {
        float s = colS[j], q = colQ[j];
        s += __shfl_xor(s, 16); s += __shfl_xor(s, 32);
        q += __shfl_xor(q, 16); q += __shfl_xor(q, 32);
        if (lq == 0) {
            int col = bn + wn * 64 + j * 16 + lr;
            atomicAdd(&colsum[col], s);
            atomicAdd(&colsumsq[col], q);
        }
    }
}

// ---------- kernel 4: finalize BN params ----------
__global__ __launch_bounds__(256) void finalize_kernel(
        const float* __restrict__ colsum, const float* __restrict__ colsumsq,
        const float* __restrict__ gamma, const float* __restrict__ beta,
        float* __restrict__ scale, float* __restrict__ bias) {
    int n = blockIdx.x * 256 + threadIdx.x;
    if (n < OUT_DIM) {
        const float inv = 1.f / (float)B_DIM;
        float mean = colsum[n] * inv;
        float var  = colsumsq[n] * inv - mean * mean;
        float sc   = gamma[n] * rsqrtf(var + BN_EPS);
        scale[n] = sc;
        bias[n]  = beta[n] - mean * sc;
    }
}

// ---------- kernel 5: bf16 Y -> affine+ReLU -> fp32 out. 8 elems/thread ----------
__global__ __launch_bounds__(256) void bn_relu_bf16_kernel(
        const u16x4* __restrict__ yb, float4* __restrict__ out,
        const float4* __restrict__ scale4, const float4* __restrict__ bias4) {
    int base = blockIdx.x * 512 + threadIdx.x;   // block covers 512 f4-groups
#pragma unroll
    for (int p = 0; p < 2; ++p) {
        int id = base + p * 256;                 // coalesced both passes
        int c4 = id & (OUT_DIM / 4 - 1);         // column group (2048%4==0)
        u16x4 h = yb[id];                        // 8B coalesced read
        float4 s = scale4[c4];
        float4 bb = bias4[c4];
        float4 v;
        v.x = fmaxf(fmaf(bf2f(h[0]), s.x, bb.x), 0.f);
        v.y = fmaxf(fmaf(bf2f(h[1]), s.y, bb.y), 0.f);
        v.z = fmaxf(fmaf(bf2f(h[2]), s.z, bb.z), 0.f);
        v.w = fmaxf(fmaf(bf2f(h[3]), s.w, bb.w), 0.f);
        out[id] = v;                             // 16B coalesced write
    }
}

// ---------- launch ----------
extern "C" void kernel_launch(void* const* d_in, const int* in_sizes, int n_in,
                              void* d_out, int out_size, void* d_ws, size_t ws_size,
                              hipStream_t stream) {
    const float* x     = (const float*)d_in[0];   // [16384, 2048]
    const float* w     = (const float*)d_in[1];   // [2048, 2048]
    const float* gamma = (const float*)d_in[2];   // [2048]
    const float* beta  = (const float*)d_in[3];   // [2048]
    float* out = (float*)d_out;                   // [16384, 2048]

    char* ws = (char*)d_ws;
    // ws layout: xq 32MB | wq 4MB | yb 64MB | stats 32KB | scales 64KB
    const size_t XQ_OFF = 0;
    const size_t WQ_OFF = XQ_OFF + (size_t)B_DIM * IN_DIM;          // 33,554,432
    const size_t YB_OFF = WQ_OFF + (size_t)OUT_DIM * IN_DIM;        // 37,748,736
    const size_t ST_OFF = YB_OFF + (size_t)B_DIM * OUT_DIM * 2;     // 104,857,600
    const size_t SC_OFF = ST_OFF + 8192 * 4;                        // 104,890,368

    char* xq = ws + XQ_OFF;
    char* wq = ws + WQ_OFF;
    unsigned short* yb = (unsigned short*)(ws + YB_OFF);
    float* colsum   = (float*)(ws + ST_OFF);
    float* colsumsq = colsum + 2048;
    float* scale    = colsum + 4096;
    float* bias     = colsum + 6144;
    float* scales   = (float*)(ws + SC_OFF);      // per-row x scales [16384]

    quantize_x_kernel<<<B_DIM, 256, 0, stream>>>(
        (const float4*)x, (int*)xq, scales);
    convert_w_kernel<<<4096, 256, 0, stream>>>(
        (const float4*)w, (int*)wq, (float4*)colsum);
    gemm_bn_kernel<<<1024, 512, 0, stream>>>(
        xq, wq, scales, yb, colsum, colsumsq);
    finalize_kernel<<<8, 256, 0, stream>>>(
        colsum, colsumsq, gamma, beta, scale, bias);
    bn_relu_bf16_kernel<<<16384, 256, 0, stream>>>(
        (const u16x4*)yb, (float4*)out, (const float4*)scale,
        (const float4*)bias);
}

// Round 3
// 331.241 us; speedup vs baseline: 1.0124x; 1.0124x over previous
//
#include <hip/hip_runtime.h>
#include <stdint.h>

// Problem constants (from reference setup_inputs)
#define B_DIM   16384
#define IN_DIM  2048
#define OUT_DIM 2048
#define BN_EPS  1e-5f

typedef int    i32x4 __attribute__((ext_vector_type(4)));
typedef unsigned short u16x4 __attribute__((ext_vector_type(4)));

// ---------- helpers ----------

__device__ __forceinline__ unsigned short f2bf_rne(float f) {
    unsigned u = __builtin_bit_cast(unsigned, f);
    return (unsigned short)((u + 0x7fffu + ((u >> 16) & 1u)) >> 16);
}
__device__ __forceinline__ float bf2f(unsigned short h) {
    unsigned u = ((unsigned)h) << 16;
    return __builtin_bit_cast(float, u);
}

// async global->LDS, 16B per lane. LDS dst = wave-uniform base + lane*16.
__device__ __forceinline__ void gl_lds16(const void* g, void* l) {
    __builtin_amdgcn_global_load_lds(
        (const __attribute__((address_space(1))) unsigned int*)g,
        (__attribute__((address_space(3))) unsigned int*)l,
        16, 0, 0);
}

__device__ __forceinline__ int pack4(float a, float b, float c, float d, float inv) {
    int q0 = (int)rintf(a * inv) & 255;
    int q1 = (int)rintf(b * inv) & 255;
    int q2 = (int)rintf(c * inv) & 255;
    int q3 = (int)rintf(d * inv) & 255;
    return q0 | (q1 << 8) | (q2 << 16) | (q3 << 24);
}

// ---------- kernel 1: x fp32 -> i8 with per-row scale ----------
__global__ __launch_bounds__(256) void quantize_x_kernel(
        const float4* __restrict__ x4, int* __restrict__ xq,
        float* __restrict__ scales) {
    __shared__ float wmax[4];
    const int row = blockIdx.x;
    const int t = threadIdx.x;
    const float4* xr = x4 + (size_t)row * 512;
    float4 a = xr[t];          // 16B coalesced
    float4 b = xr[t + 256];
    float m = fmaxf(fmaxf(fabsf(a.x), fabsf(a.y)), fmaxf(fabsf(a.z), fabsf(a.w)));
    m = fmaxf(m, fmaxf(fmaxf(fabsf(b.x), fabsf(b.y)), fmaxf(fabsf(b.z), fabsf(b.w))));
#pragma unroll
    for (int off = 32; off >= 1; off >>= 1) m = fmaxf(m, __shfl_xor(m, off));
    if ((t & 63) == 0) wmax[t >> 6] = m;
    __syncthreads();
    m = fmaxf(fmaxf(wmax[0], wmax[1]), fmaxf(wmax[2], wmax[3]));
    m = fmaxf(m, 1e-20f);                 // guard all-zero row
    const float inv = 127.0f / m;
    if (t == 0) scales[row] = m * (1.0f / 127.0f);
    int* xo = xq + (size_t)row * 512;
    xo[t]       = pack4(a.x, a.y, a.z, a.w, inv);   // 4B coalesced
    xo[t + 256] = pack4(b.x, b.y, b.z, b.w, inv);
}

// ---------- kernel 2: w fp32 -> sign i8 (+1/-1); also zero stat accums ----------
__global__ __launch_bounds__(256) void convert_w_kernel(
        const float4* __restrict__ w, int* __restrict__ wq,
        float4* __restrict__ stats /* colsum[2048]+colsumsq[2048] */) {
    int id = blockIdx.x * 256 + threadIdx.x;       // exact: 4096 blocks
    if (id < 1024) stats[id] = make_float4(0.f, 0.f, 0.f, 0.f);
    float4 a = w[id];
    int b0 = (a.x < 0.f) ? 0xFF : 0x01;
    int b1 = (a.y < 0.f) ? 0xFF : 0x01;
    int b2 = (a.z < 0.f) ? 0xFF : 0x01;
    int b3 = (a.w < 0.f) ? 0xFF : 0x01;
    wq[id] = b0 | (b1 << 8) | (b2 << 16) | (b3 << 24);
}

// ---------- kernel 3: i8 GEMM (NT) 256x256 tile, BK=128, loose 2-barrier loop ----------
// Round-3 theory: r1 (8-phase lockstep) and r2 (64x64 waves) both stall at ~37%
// MfmaUtil because each barrier window carries too little MFMA to amortize the
// fixed window overhead (barrier + lgkm/vmcnt drain). This round:
//  - r1 geometry: wave tile 128x64, BK=128 (full 128B-line fetches -> FETCH
//    back to ~50MB), proven XOR swizzle (0 conflicts)
//  - r2 loop: ONE window per K-tile -> 64 MFMA/wave between barriers,
//    2 barriers + 1 counted vmcnt per 128 K-bytes, no forced lgkmcnt(0)
//    (compiler emits counted lgkm waits between ds_read and dependent MFMA)
//  - 512 thr = 8 waves (2M x 4N), 2 waves/SIMD: TLP hides read latency
//  - LDS 128 KB dbuf; 1 block/CU; grid 512 (2 rounds)
__global__ __launch_bounds__(512, 2) void gemm_bn_kernel(
        const char* __restrict__ A, const char* __restrict__ Bw,
        const float* __restrict__ scales,
        unsigned short* __restrict__ Yb,
        float* __restrict__ colsum, float* __restrict__ colsumsq) {
    __shared__ __align__(16) char smem[131072];  // [2 buf][A 32K | B 32K]

    const int tid  = threadIdx.x;
    const int wave = tid >> 6;
    const int lane = tid & 63;
    const int wm = wave >> 2;         // 0..1 -> 128-row band of M
    const int wn = wave & 3;          // 0..3 -> 64-col band of N
    const int lr = lane & 15;
    const int lq = lane >> 4;

    // XCD swizzle (512 blocks, 512%8==0 -> simple bijection)
    const int b  = blockIdx.x;                 // 0..511
    const int lb = (b & 7) * 64 + (b >> 3);
    const int bm = (lb >> 3) * 256;            // 64 M tiles
    const int bn = (lb & 7) * 256;             // 8 N tiles

    // ---- staging addressing ----
    // sweep = 64 rows x 128B = 8KB = 512 thr x 16B; thread row = tid>>3,
    // chunk = tid&7; source chunk = chunk ^ (row&7) (sweep bases %8==0).
    const int swz16 = (((tid & 7) ^ ((tid >> 3) & 7)) << 4);
    const char* gA = A  + (size_t)(bm + (tid >> 3)) * IN_DIM + swz16;
    const char* gB = Bw + (size_t)(bn + (tid >> 3)) * IN_DIM + swz16;
    const int ldst = tid << 4;

    // ---- ds-read addressing ----
    // A frag (i,kk): row = wm*128 + i*16 + lr (x128B), slot = (kk*4+lq)^(lr&7)
    const int aRd = wm * 16384 + lr * 128;
    const int bRd = 32768 + wn * 8192 + lr * 128;
    const int sl0 = ((lq    ) ^ (lr & 7)) << 4;
    const int sl1 = ((lq + 4) ^ (lr & 7)) << 4;

    i32x4 acc[8][4];
#pragma unroll
    for (int i = 0; i < 8; ++i)
#pragma unroll
        for (int j = 0; j < 4; ++j) {
            i32x4 z = {0, 0, 0, 0};
            acc[i][j] = z;
        }

#define VM_WAIT(N) asm volatile("s_waitcnt vmcnt(" #N ")" ::: "memory")
#define BAR()      __builtin_amdgcn_s_barrier()
// stage one 64KB K-tile (A 32K + B 32K) into buffer buf_: 8 sweeps
#define STAGE(buf_, k_) do {                                        \
    char* d = smem + (buf_) * 65536;                                \
    gl_lds16(gA + (k_)          , d + 0 * 8192 + ldst);             \
    gl_lds16(gA + (k_) + 131072 , d + 1 * 8192 + ldst);             \
    gl_lds16(gA + (k_) + 262144 , d + 2 * 8192 + ldst);             \
    gl_lds16(gA + (k_) + 393216 , d + 3 * 8192 + ldst);             \
    gl_lds16(gB + (k_)          , d + 32768 + 0 * 8192 + ldst);     \
    gl_lds16(gB + (k_) + 131072 , d + 32768 + 1 * 8192 + ldst);     \
    gl_lds16(gB + (k_) + 262144 , d + 32768 + 2 * 8192 + ldst);     \
    gl_lds16(gB + (k_) + 393216 , d + 32768 + 3 * 8192 + ldst);     \
} while (0)

    // prologue: tiles 0,1 -> buffers 0,1; drain tile 0's 8 loads only
    STAGE(0, 0);
    STAGE(1, 128);
    VM_WAIT(8);
    BAR();

    const int NT = IN_DIM / 128;    // 16 K-tiles
#pragma unroll 2
    for (int t = 0; t < NT; ++t) {
        const char* Sb = smem + (t & 1) * 65536;
        // ---- kk = 0 ----
        {
            i32x4 av[8], bv[4];
#pragma unroll
            for (int i = 0; i < 8; ++i)
                av[i] = *(const i32x4*)(Sb + aRd + i * 2048 + sl0);
#pragma unroll
            for (int j = 0; j < 4; ++j)
                bv[j] = *(const i32x4*)(Sb + bRd + j * 2048 + sl0);
            __builtin_amdgcn_s_setprio(1);
#pragma unroll
            for (int i = 0; i < 8; ++i)
#pragma unroll
                for (int j = 0; j < 4; ++j)
                    acc[i][j] = __builtin_amdgcn_mfma_i32_16x16x64_i8(
                        av[i], bv[j], acc[i][j], 0, 0, 0);
            __builtin_amdgcn_s_setprio(0);
        }
        // ---- kk = 1 ----
        {
            i32x4 av[8], bv[4];
#pragma unroll
            for (int i = 0; i < 8; ++i)
                av[i] = *(const i32x4*)(Sb + aRd + i * 2048 + sl1);
#pragma unroll
            for (int j = 0; j < 4; ++j)
                bv[j] = *(const i32x4*)(Sb + bRd + j * 2048 + sl1);
            __builtin_amdgcn_s_setprio(1);
#pragma unroll
            for (int i = 0; i < 8; ++i)
#pragma unroll
                for (int j = 0; j < 4; ++j)
                    acc[i][j] = __builtin_amdgcn_mfma_i32_16x16x64_i8(
                        av[i], bv[j], acc[i][j], 0, 0, 0);
            __builtin_amdgcn_s_setprio(0);
        }

        if (t + 2 < NT) {
            BAR();                               // all waves done reading Sb
            STAGE(t & 1, (size_t)(t + 2) * 128); // overwrite with tile t+2
            VM_WAIT(8);                          // drain t+1; t+2 in flight
            BAR();                               // t+1 visible to all waves
        } else if (t + 1 < NT) {
            VM_WAIT(0);                          // drain final tile's loads
            BAR();
        }
    }

#undef STAGE
#undef VM_WAIT
#undef BAR

    // epilogue: y = scales[m] * acc (C/D layout: col = lr, row = lq*4 + r)
    float colS[4], colQ[4];
#pragma unroll
    for (int j = 0; j < 4; ++j) { colS[j] = 0.f; colQ[j] = 0.f; }

#pragma unroll
    for (int i = 0; i < 8; ++i) {
        const int row0 = bm + wm * 128 + i * 16 + lq * 4;
        float sc[4];
#pragma unroll
        for (int r = 0; r < 4; ++r) sc[r] = scales[row0 + r];
#pragma unroll
        for (int r = 0; r < 4; ++r) {
            size_t base = (size_t)(row0 + r) * OUT_DIM + bn + wn * 64 + lr;
#pragma unroll
            for (int j = 0; j < 4; ++j) {
                float v = (float)acc[i][j][r] * sc[r];
                Yb[base + j * 16] = f2bf_rne(v);
                colS[j] += v;
                colQ[j] += v * v;
            }
        }
    }

    // per-column partial sum / sumsq -> atomics (combine 4 quads = 4 row groups)
#pragma unroll
    for (int j = 0; j < 4; ++j) {
        float s = colS[j], q = colQ[j];
        s += __shfl_xor(s, 16); s += __shfl_xor(s, 32);
        q += __shfl_xor(q, 16); q += __shfl_xor(q, 32);
        if (lq == 0) {
            int col = bn + wn * 64 + j * 16 + lr;
            atomicAdd(&colsum[col], s);
            atomicAdd(&colsumsq[col], q);
        }
    }
}

// ---------- kernel 4: finalize BN params ----------
__global__ __launch_bounds__(256) void finalize_kernel(
        const float* __restrict__ colsum, const float* __restrict__ colsumsq,
        const float* __restrict__ gamma, const float* __restrict__ beta,
        float* __restrict__ scale, float* __restrict__ bias) {
    int n = blockIdx.x * 256 + threadIdx.x;
    if (n < OUT_DIM) {
        const float inv = 1.f / (float)B_DIM;
        float mean = colsum[n] * inv;
        float var  = colsumsq[n] * inv - mean * mean;
        float sc   = gamma[n] * rsqrtf(var + BN_EPS);
        scale[n] = sc;
        bias[n]  = beta[n] - mean * sc;
    }
}

// ---------- kernel 5: bf16 Y -> affine+ReLU -> fp32 out. 8 elems/thread ----------
__global__ __launch_bounds__(256) void bn_relu_bf16_kernel(
        const u16x4* __restrict__ yb, float4* __restrict__ out,
        const float4* __restrict__ scale4, const float4* __restrict__ bias4) {
    int base = blockIdx.x * 512 + threadIdx.x;   // block covers 512 f4-groups
#pragma unroll
    for (int p = 0; p < 2; ++p) {
        int id = base + p * 256;                 // coalesced both passes
        int c4 = id & (OUT_DIM / 4 - 1);         // column group (2048%4==0)
        u16x4 h = yb[id];                        // 8B coalesced read
        float4 s = scale4[c4];
        float4 bb = bias4[c4];
        float4 v;
        v.x = fmaxf(fmaf(bf2f(h[0]), s.x, bb.x), 0.f);
        v.y = fmaxf(fmaf(bf2f(h[1]), s.y, bb.y), 0.f);
        v.z = fmaxf(fmaf(bf2f(h[2]), s.z, bb.z), 0.f);
        v.w = fmaxf(fmaf(bf2f(h[3]), s.w, bb.w), 0.f);
        out[id] = v;                             // 16B coalesced write
    }
}

// ---------- launch ----------
extern "C" void kernel_launch(void* const* d_in, const int* in_sizes, int n_in,
                              void* d_out, int out_size, void* d_ws, size_t ws_size,
                              hipStream_t stream) {
    const float* x     = (const float*)d_in[0];   // [16384, 2048]
    const float* w     = (const float*)d_in[1];   // [2048, 2048]
    const float* gamma = (const float*)d_in[2];   // [2048]
    const float* beta  = (const float*)d_in[3];   // [2048]
    float* out = (float*)d_out;                   // [16384, 2048]

    char* ws = (char*)d_ws;
    // ws layout: xq 32MB | wq 4MB | yb 64MB | stats 32KB | scales 64KB
    const size_t XQ_OFF = 0;
    const size_t WQ_OFF = XQ_OFF + (size_t)B_DIM * IN_DIM;          // 33,554,432
    const size_t YB_OFF = WQ_OFF + (size_t)OUT_DIM * IN_DIM;        // 37,748,736
    const size_t ST_OFF = YB_OFF + (size_t)B_DIM * OUT_DIM * 2;     // 104,857,600
    const size_t SC_OFF = ST_OFF + 8192 * 4;                        // 104,890,368

    char* xq = ws + XQ_OFF;
    char* wq = ws + WQ_OFF;
    unsigned short* yb = (unsigned short*)(ws + YB_OFF);
    float* colsum   = (float*)(ws + ST_OFF);
    float* colsumsq = colsum + 2048;
    float* scale    = colsum + 4096;
    float* bias     = colsum + 6144;
    float* scales   = (float*)(ws + SC_OFF);      // per-row x scales [16384]

    quantize_x_kernel<<<B_DIM, 256, 0, stream>>>(
        (const float4*)x, (int*)xq, scales);
    convert_w_kernel<<<4096, 256, 0, stream>>>(
        (const float4*)w, (int*)wq, (float4*)colsum);
    gemm_bn_kernel<<<512, 512, 0, stream>>>(
        xq, wq, scales, yb, colsum, colsumsq);
    finalize_kernel<<<8, 256, 0, stream>>>(
        colsum, colsumsq, gamma, beta, scale, bias);
    bn_relu_bf16_kernel<<<16384, 256, 0, stream>>>(
        (const u16x4*)yb, (float4*)out, (const float4*)scale,
        (const float4*)bias);
}